// Round 1
// baseline (134.523 us; speedup 1.0000x reference)
//
#include <hip/hip_runtime.h>

#define BN 256   // batches
#define NN 256   // matrix dim
#define WL 8     // walk length

typedef __attribute__((ext_vector_type(4))) float f32x4;
typedef __attribute__((ext_vector_type(8))) int   i32x8;
typedef unsigned long long ull;

// Segment fence: kills LICM/hoisting of LDS loads across it (all memory
// appears clobbered). Without it, all per-step A-frag loads are
// g-loop-invariant and LICM hoists ~256 VGPRs of A-frags out of the
// g-loop -> spill (proven in earlier rounds). SSA registers are NOT
// spilled by the clobber.
#define SEG_FENCE() __asm__ volatile("" ::: "memory")

// MX-scaled MFMA, fp8 e4m3 both operands (fmt code 0), scales = 1.0
// (E8M0 byte 0x7f = 2^0; replicated so any op_sel byte choice is 1.0).
// Runs at the MX rate (~4661 TF measured) = 2.27x plain fp8 MFMA.
#define MFMA128(A, B, C) \
  __builtin_amdgcn_mfma_scale_f32_16x16x128_f8f6f4( \
      (A), (B), (C), 0, 0, 0, 0x7f7f7f7f, 0, 0x7f7f7f7f)

// ---- f32 -> fp8 e4m3fn (OCP), RNE; manual fallback if builtin absent -------
__device__ inline unsigned f2e4m3(float x) {
  union { float f; unsigned u; } v; v.f = x;
  if (v.f <= 0.0f) return 0;                       // inputs are >= 0 here
  int e = (int)((v.u >> 23) & 0xff) - 127;
  if (e < -9) return 0;
  if (e < -6) {                                    // subnormal: q = RNE(x*512)
    int qi = (int)(x * 512.0f + 0.5f);
    return qi > 7 ? 7u : (unsigned)qi;
  }
  unsigned r = v.u + 0x7ffff + ((v.u >> 20) & 1);  // RNE to 3 mantissa bits
  e = (int)((r >> 23) & 0xff) - 127;
  unsigned m = (r >> 20) & 7;
  return (unsigned)(((e + 7) << 3) | m);
}

__device__ inline unsigned pk4(float a, float b, float c, float d) {
#if __has_builtin(__builtin_amdgcn_cvt_pk_fp8_f32)
  int r = 0;
  r = __builtin_amdgcn_cvt_pk_fp8_f32(a, b, r, false);   // bytes 0,1
  r = __builtin_amdgcn_cvt_pk_fp8_f32(c, d, r, true);    // bytes 2,3
  return (unsigned)r;
#else
  return f2e4m3(a) | (f2e4m3(b) << 8) | (f2e4m3(c) << 16) | (f2e4m3(d) << 24);
#endif
}

__device__ __forceinline__ i32x8 as8(const long* p) {
  union { long l[4]; i32x8 v; } u;
  u.l[0] = p[0]; u.l[1] = p[1]; u.l[2] = p[2]; u.l[3] = p[3];
  return u.v;
}

// ---- fused kernel: one block (16 waves, 1024 thr) per batch ----------------
// LDS: S = 64*P, fp8 e4m3, row-major with 8B-granule XOR swizzle:
//   byte(row,col) at row*256 + ((col>>3) ^ (row&31))*8 + (col&7)
//
// Chain now uses mfma_scale_f32_16x16x128_f8f6f4 (fmt=fp8, scale=1.0):
//   A-frag(tile rt, kblock kb): lane (r=l16, q) holds bytes k = 128kb+32q+j,
//     j=0..31 -> 4 swizzled b64 granules (16kb+4q+i)^(row&31). Low-4-bit
//     pattern (4q+i)^l16 == the old (4kt+q)^l16 structure -> same benign
//     bank behavior.
//   B-frag: lane (col=l16, q) holds k = 128kb+32q+j -> bcur0/bcur1 (i32x8).
//   C layout unchanged (col=l16, row=4q+reg) -> diag extraction identical.
//
// Per segment pt (row tiles 2pt,2pt+1; k-range [32pt,32pt+32)): 16 b64
// A-prefetch (next segment, parity dbuf as before) + 4 MFMA (two 2-deep
// acc chains, was 16 in 8-deep chains). Retire: this segment's 32 k-rows
// belong entirely to quad q'=pt&3 of block kb=pt>>2: 8 bpermutes broadcast
// the packed dwords; lanes with q==pt&3 capture all 8 (static indices only
// -- runtime-indexed vectors go to scratch).
__global__ __launch_bounds__(1024, 1) void k_chain(const float* __restrict__ A,
                                                   float* __restrict__ out) {
  __shared__ unsigned char S[65536];
  int b  = blockIdx.x;
  int t  = threadIdx.x;
  int wi = t >> 6;                 // wave 0..15
  int l  = t & 63;
  int q  = l >> 4, l16 = l & 15;
  const float* Ab = A + (size_t)b * NN * NN;
  float* outb = out + (size_t)b * NN * WL;

  // ---- phase 1: prep. wave wi handles rows [16wi, 16wi+16).
  for (int r0 = wi * 16; r0 < wi * 16 + 16; r0 += 8) {
    float4 rv[8];                                   // 8-deep load pipeline
    #pragma unroll
    for (int i = 0; i < 8; i++)
      rv[i] = *(const float4*)(Ab + (size_t)(r0 + i) * NN + l * 4);
    #pragma unroll
    for (int i = 0; i < 8; i++) {
      int row = r0 + i;                             // wave-uniform
      float t0 = rv[i].x > 0.3f ? rv[i].x : 0.0f;
      float t1 = rv[i].y > 0.3f ? rv[i].y : 0.0f;
      float t2 = rv[i].z > 0.3f ? rv[i].z : 0.0f;
      float t3 = rv[i].w > 0.3f ? rv[i].w : 0.0f;
      float s = (t0 + t1) + (t2 + t3);
      #pragma unroll
      for (int o = 32; o; o >>= 1) s += __shfl_xor(s, o);
      float dinv = s > 0.0f ? 1.0f / s : 0.0f;
      int rm = row & 3;                             // uniform
      float tv = rm == 0 ? t0 : rm == 1 ? t1 : rm == 2 ? t2 : t3;
      if (l == (row >> 2)) {
        outb[row * WL + 0] = 1.0f;
        outb[row * WL + 1] = tv * dinv;             // diag(P), exact f32
      }
      float sc = dinv * 64.0f;                      // store S = 64*P
      unsigned pkd = pk4(t0 * sc, t1 * sc, t2 * sc, t3 * sc);
      unsigned addr = row * 256 + ((((unsigned)l >> 1) ^ (row & 31)) << 3) + ((l & 1) << 2);
      *(unsigned*)&S[addr] = pkd;
    }
  }
  __syncthreads();   // S complete; read-only hereafter

  // ---- phase 2: identity B-frags (X0 = I) for the wave's 16-col strip.
  // Lane (col n=16wi+l16, quad q) owns k = 128kb + 32q + j. k==n needs
  // kb = n>>7, q == (n>>5)&3, byte j = n&31 set to e4m3 1.0 (0x38).
  i32x8 bcur0 = (i32x8)0, bcur1 = (i32x8)0;
  int n = 16 * wi + l16;           // this lane's owned column
  {
    bool qm = (((n >> 5) & 3) == q);
    unsigned w = 0x38u << (8 * (n & 3));
    #pragma unroll
    for (int d = 0; d < 8; d++) {
      bcur0[d] = (qm && (n >> 7) == 0 && ((n >> 2) & 7) == d) ? (int)w : 0;
      bcur1[d] = (qm && (n >> 7) == 1 && ((n >> 2) & 7) == d) ? (int)w : 0;
    }
  }

  // ---- phase 3: chain with one-segment-ahead A prefetch.
  const float invQ = 1.0f / 4096.0f;
  const float inv64 = 1.0f / 64.0f;
  int dpt = wi >> 1, dmtl = wi & 1;   // segment/half holding this wave's diag

  long abuf[2][2][2][4];              // [parity][tile01][kb][granule]
  int bn0[8], bn1[8];
  #pragma unroll
  for (int d = 0; d < 8; d++) { bn0[d] = 0; bn1[d] = 0; }

  // preload segment 0 into parity 0
  {
    int r0 = l16, r1 = l16 + 16;
    #pragma unroll
    for (int kb = 0; kb < 2; kb++)
      #pragma unroll
      for (int i = 0; i < 4; i++) {
        int gg = 16 * kb + 4 * q + i;
        abuf[0][0][kb][i] = *(const long*)&S[r0 * 256 + ((gg ^ (r0 & 31)) << 3)];
        abuf[0][1][kb][i] = *(const long*)&S[r1 * 256 + ((gg ^ (r1 & 31)) << 3)];
      }
  }

  #pragma unroll 1
  for (int g = 1; g <= 7; g++) {
    float osc = (g == 1) ? 1.0f : inv64;            // bnext scale
    #pragma unroll
    for (int pt = 0; pt < 8; pt++) {                // tiles mt = 2pt, 2pt+1
      SEG_FENCE();
      const int cur = pt & 1;
      const int nxt = (pt + 1) & 1;
      const int pn  = (pt + 1) & 7;   // wraps to seg 0 for next g (same addrs)
      // prefetch next segment's A-frags; MFMA below uses parity `cur`,
      // already resident -> no full lgkm drain on the critical path.
      {
        int r0 = 32 * pn + l16, r1 = r0 + 16;
        #pragma unroll
        for (int kb = 0; kb < 2; kb++)
          #pragma unroll
          for (int i = 0; i < 4; i++) {
            int gg = 16 * kb + 4 * q + i;
            abuf[nxt][0][kb][i] = *(const long*)&S[r0 * 256 + ((gg ^ (r0 & 31)) << 3)];
            abuf[nxt][1][kb][i] = *(const long*)&S[r1 * 256 + ((gg ^ (r1 & 31)) << 3)];
          }
      }
      f32x4 acc0 = (f32x4){0.f, 0.f, 0.f, 0.f};
      f32x4 acc1 = (f32x4){0.f, 0.f, 0.f, 0.f};
      acc0 = MFMA128(as8(abuf[cur][0][0]), bcur0, acc0);
      acc0 = MFMA128(as8(abuf[cur][0][1]), bcur1, acc0);
      acc1 = MFMA128(as8(abuf[cur][1][0]), bcur0, acc1);
      acc1 = MFMA128(as8(abuf[cur][1][1]), bcur1, acc1);
      // diag(P^g): C layout col=l16, row=4q+r. This wave's diag lives in
      // tile wi = 2*dpt + dmtl, at lanes with l16>>2 == q.
      if (g >= 2 && pt == dpt && (l16 >> 2) == q) {
        float dv = dmtl ? acc1[l16 & 3] : acc0[l16 & 3];
        outb[n * WL + g] = dv * invQ;
      }
      if (g < 7) {
        // acc -> bnext: segment pt covers k = 32pt + (4q+reg) [acc0] and
        // 32pt+16+(4q+reg) [acc1]; pack each lane's 4 k-bytes, then
        // broadcast quad d's dwords to everyone; lanes with q==pt&3 keep
        // all 8 dwords (their kb=pt>>2 block).
        unsigned pkv0 = pk4(acc0[0] * osc, acc0[1] * osc, acc0[2] * osc, acc0[3] * osc);
        unsigned pkv1 = pk4(acc1[0] * osc, acc1[1] * osc, acc1[2] * osc, acc1[3] * osc);
        bool cap = (q == (pt & 3));
        #pragma unroll
        for (int d = 0; d < 4; d++) {
          int rlo = __shfl((int)pkv0, l16 + 16 * d);   // dword d   (k=32pt+4d+c)
          int rhi = __shfl((int)pkv1, l16 + 16 * d);   // dword 4+d (k=32pt+16+4d+c)
          if (pt < 4) {
            bn0[d]     = cap ? rlo : bn0[d];
            bn0[4 + d] = cap ? rhi : bn0[4 + d];
          } else {
            bn1[d]     = cap ? rlo : bn1[d];
            bn1[4 + d] = cap ? rhi : bn1[4 + d];
          }
        }
      }
    }
    if (g < 7) {
      #pragma unroll
      for (int d = 0; d < 8; d++) {
        bcur0[d] = bn0[d];
        bcur1[d] = bn1[d];
      }
    }
  }
}

extern "C" void kernel_launch(void* const* d_in, const int* in_sizes, int n_in,
                              void* d_out, int out_size, void* d_ws, size_t ws_size,
                              hipStream_t stream) {
  const float* A = (const float*)d_in[0];
  float* out = (float*)d_out;
  k_chain<<<BN, 1024, 0, stream>>>(A, out);
}